// Round 2
// baseline (687.676 us; speedup 1.0000x reference)
//
#include <hip/hip_runtime.h>

// VanillaLstmEncDec round 2: fused persistent-per-block LSTM enc(8)+dec(11).
// Block = 64 batch rows, 512 threads (8 waves). Wave wn owns all 64 rows x
// hidden cols [16wn,16wn+16) x 4 gates -> acc[4][4] f32x4 = 64 regs.
// h in LDS bf16 (K=128 only); c in f32 regs; Whh^T (bf16) held IN REGISTERS
// (64 VGPRs), reloaded once at enc->dec switch. Input embedding is rank-2:
// folded as z += px*wx[g] + py*wy[g] in exact f32; bias pre-folded into acc
// init. Gate math uses shared-denominator form: 5 exp2 + 2 rcp per element.

#define OBS_LEN 8
#define PRED_LEN 12
#define BATCH 131072
#define HID 128
#define NZ 512          // 4*HID gate columns
#define KWT 128         // weight K (pure Whh)
#define KP 136          // LDS A row stride elems (272 B = 17*16B -> conflict-free b128)
#define ROWS 64         // batch rows per block

typedef float f32x4 __attribute__((ext_vector_type(4)));
typedef unsigned short u16x8 __attribute__((ext_vector_type(8)));
typedef __bf16 bf16x8 __attribute__((ext_vector_type(8)));

#define K2F 1.4426950408889634f   // log2(e)

static __device__ __forceinline__ unsigned short f2bf(float f) {
  unsigned int u = __float_as_uint(f);
  u += 0x7FFFu + ((u >> 16) & 1u);
  return (unsigned short)(u >> 16);
}
static __device__ __forceinline__ float bf2f(unsigned short h) {
  return __uint_as_float(((unsigned int)h) << 16);
}

// ---------------- prep: Whh^T bf16 + folded input-embedding scalars ----------
// wt[n][k] = Whh[k][n] (bf16), n in [0,512), k in [0,128)
// aux[0*512+n] = (Wemb@Wih)[0][n]; aux[1*512+n] = (Wemb@Wih)[1][n];
// aux[2*512+n] = bemb@Wih[n] + b[n]    (all f32)
__global__ void prep_weights(const float* __restrict__ We,   const float* __restrict__ be,
                             const float* __restrict__ Wih_e,const float* __restrict__ Whh_e,
                             const float* __restrict__ b_e,
                             const float* __restrict__ Wd,   const float* __restrict__ bd,
                             const float* __restrict__ Wih_d,const float* __restrict__ Whh_d,
                             const float* __restrict__ b_d,
                             unsigned short* __restrict__ wt_enc,
                             unsigned short* __restrict__ wt_dec,
                             float* __restrict__ aux_enc, float* __restrict__ aux_dec) {
  int n = blockIdx.x & (NZ - 1);
  bool dec = blockIdx.x >= NZ;
  const float* Whh = dec ? Whh_d : Whh_e;
  const float* Wih = dec ? Wih_d : Wih_e;
  const float* Wem = dec ? Wd : We;
  const float* bem = dec ? bd : be;
  const float* bl  = dec ? b_d : b_e;
  unsigned short* wt = dec ? wt_dec : wt_enc;
  float* aux = dec ? aux_dec : aux_enc;
  int t = threadIdx.x;
  for (int k = t; k < KWT; k += 64) wt[n * KWT + k] = f2bf(Whh[k * NZ + n]);
  if (t < 3) {
    float s = (t == 2) ? bl[n] : 0.f;
    const float* ve = (t == 0) ? Wem : (t == 1) ? (Wem + HID) : bem;
    for (int e = 0; e < HID; ++e) s += ve[e] * Wih[e * NZ + n];
    aux[t * NZ + n] = s;
  }
}

// ---------------- main fused kernel ----------------
// MFMA 16x16x32 bf16: A row = lane&15, k = 32kc + (lane>>4)*8 + j (verified r1)
// C/D: col = lane&15, row = (lane>>4)*4 + reg (verified r1)

#define LOADW(WT, AUX)                                                         \
  {                                                                            \
    _Pragma("unroll")                                                          \
    for (int kc = 0; kc < 4; ++kc) {                                           \
      _Pragma("unroll")                                                        \
      for (int g = 0; g < 4; ++g)                                              \
        bfr[kc][g] = *(const u16x8*)&(WT)[(g * 128 + wn * 16 + l15) * KWT +    \
                                          kc * 32 + l4 * 8];                   \
    }                                                                          \
    _Pragma("unroll")                                                          \
    for (int g = 0; g < 4; ++g) {                                              \
      int n_ = g * 128 + wn * 16 + l15;                                        \
      wx[g] = (AUX)[n_]; wy[g] = (AUX)[NZ + n_]; bb[g] = (AUX)[2 * NZ + n_];   \
    }                                                                          \
  }

#define STEP_MM()                                                              \
  {                                                                            \
    _Pragma("unroll")                                                          \
    for (int m = 0; m < 4; ++m) {                                              \
      _Pragma("unroll")                                                        \
      for (int g = 0; g < 4; ++g)                                              \
        acc[m][g] = (f32x4){bb[g], bb[g], bb[g], bb[g]};                       \
    }                                                                          \
    _Pragma("unroll")                                                          \
    for (int kc = 0; kc < 4; ++kc) {                                           \
      const int k0 = kc * 32 + l4 * 8;                                         \
      u16x8 afr[4];                                                            \
      _Pragma("unroll")                                                        \
      for (int m = 0; m < 4; ++m)                                              \
        afr[m] = *(const u16x8*)&Als[(16 * m + l15) * KP + k0];                \
      _Pragma("unroll")                                                        \
      for (int g = 0; g < 4; ++g) {                                            \
        _Pragma("unroll")                                                      \
        for (int m = 0; m < 4; ++m)                                            \
          acc[m][g] = __builtin_amdgcn_mfma_f32_16x16x32_bf16(                 \
              __builtin_bit_cast(bf16x8, afr[m]),                              \
              __builtin_bit_cast(bf16x8, bfr[kc][g]), acc[m][g], 0, 0, 0);     \
      }                                                                        \
    }                                                                          \
  }

// gate phase: input fold (exact f32) + shared-denominator gates + h write
#define GATE_PHASE(PBUF)                                                       \
  {                                                                            \
    _Pragma("unroll")                                                          \
    for (int m = 0; m < 4; ++m) {                                              \
      f32x4 pA = *(const f32x4*)&(PBUF)[(16 * m + l4 * 4) * 2];                \
      f32x4 pB = *(const f32x4*)&(PBUF)[(16 * m + l4 * 4 + 2) * 2];            \
      float px[4] = {pA[0], pA[2], pB[0], pB[2]};                              \
      float py[4] = {pA[1], pA[3], pB[1], pB[3]};                              \
      _Pragma("unroll")                                                        \
      for (int r = 0; r < 4; ++r) {                                            \
        float zi = acc[m][0][r] + px[r] * wx[0] + py[r] * wy[0];               \
        float zf = acc[m][1][r] + px[r] * wx[1] + py[r] * wy[1];               \
        float zg = acc[m][2][r] + px[r] * wx[2] + py[r] * wy[2];               \
        float zo = acc[m][3][r] + px[r] * wx[3] + py[r] * wy[3];               \
        float eA = __builtin_amdgcn_exp2f(-K2F * zf);                          \
        float eB = __builtin_amdgcn_exp2f(-K2F * zi);                          \
        float eG = __builtin_amdgcn_exp2f(-2.f * K2F * zg);                    \
        float eO = __builtin_amdgcn_exp2f(-K2F * zo);                          \
        float a1 = 1.f + eA, b1 = 1.f + eB, g1 = 1.f + eG;                     \
        float num = cr[m][r] * b1 * g1 + (1.f - eG) * a1;                      \
        float c = num * __builtin_amdgcn_rcpf(a1 * b1 * g1);                   \
        cr[m][r] = c;                                                          \
        float eC = __builtin_amdgcn_exp2f(-2.f * K2F * c);                     \
        float h = (1.f - eC) * __builtin_amdgcn_rcpf((1.f + eO) * (1.f + eC)); \
        Als[(16 * m + l4 * 4 + r) * KP + wn * 16 + l15] = f2bf(h);             \
      }                                                                        \
    }                                                                          \
  }

#define STAGE_OBS(T, PBUF)                                                     \
  if (tid < ROWS) {                                                            \
    float2 p = ((const float2*)obs)[(size_t)(T)*BATCH + row0 + tid];           \
    (PBUF)[tid * 2] = p.x; (PBUF)[tid * 2 + 1] = p.y;                          \
  }

// pos = h @ Wo + bo. 8 threads per row, each covers 16 k; shfl-reduce.
#define POS_PHASE(S)                                                           \
  {                                                                            \
    const int r = tid >> 3, q = tid & 7;                                       \
    u16x8 h0 = *(const u16x8*)&Als[r * KP + q * 16];                           \
    u16x8 h1 = *(const u16x8*)&Als[r * KP + q * 16 + 8];                       \
    float sx = 0.f, sy = 0.f;                                                  \
    _Pragma("unroll")                                                          \
    for (int j = 0; j < 8; ++j) {                                              \
      float ha = bf2f(h0[j]), hb = bf2f(h1[j]);                                \
      int k = q * 16 + j;                                                      \
      sx += ha * WoL[k][0] + hb * WoL[k + 8][0];                               \
      sy += ha * WoL[k][1] + hb * WoL[k + 8][1];                               \
    }                                                                          \
    sx += __shfl_xor(sx, 1); sx += __shfl_xor(sx, 2); sx += __shfl_xor(sx, 4); \
    sy += __shfl_xor(sy, 1); sy += __shfl_xor(sy, 2); sy += __shfl_xor(sy, 4); \
    if (q == 0) {                                                              \
      float pxv = sx + bo0, pyv = sy + bo1;                                    \
      float2 o; o.x = pxv; o.y = pyv;                                          \
      ((float2*)out)[(size_t)(S)*BATCH + row0 + r] = o;                        \
      posL[0][r * 2] = pxv; posL[0][r * 2 + 1] = pyv;                          \
    }                                                                          \
  }

__global__ __launch_bounds__(512, 2) void lstm_fused(
    const float* __restrict__ obs,
    const unsigned short* __restrict__ wt_enc,
    const unsigned short* __restrict__ wt_dec,
    const float* __restrict__ aux_enc, const float* __restrict__ aux_dec,
    const float* __restrict__ Wo, const float* __restrict__ bo,
    float* __restrict__ out) {
  __shared__ unsigned short Als[ROWS * KP];
  __shared__ float posL[2][ROWS * 2];
  __shared__ float WoL[HID][2];

  const int tid = threadIdx.x;
  const int lane = tid & 63;
  const int wn = tid >> 6;        // 0..7: hidden cols [16wn,16wn+16)
  const int l15 = lane & 15;
  const int l4 = lane >> 4;
  const int row0 = blockIdx.x * ROWS;

  for (int i = tid; i < ROWS * KP; i += 512) Als[i] = 0;  // h=0
  if (tid < HID) { WoL[tid][0] = Wo[tid * 2]; WoL[tid][1] = Wo[tid * 2 + 1]; }
  const float bo0 = bo[0], bo1 = bo[1];

  u16x8 bfr[4][4];         // B fragments, [kc][gate] — persistent
  float wx[4], wy[4], bb[4];
  LOADW(wt_enc, aux_enc);

  f32x4 acc[4][4];         // [m][gate]
  float cr[4][4];
#pragma unroll
  for (int m = 0; m < 4; ++m) {
#pragma unroll
    for (int r = 0; r < 4; ++r) cr[m][r] = 0.f;
  }

  STAGE_OBS(0, posL[0]);
  __syncthreads();

  // ---- encoder ----
  for (int t = 0; t < OBS_LEN; ++t) {
    STEP_MM();
    __syncthreads();                 // all waves done reading Als
    GATE_PHASE(posL[t & 1]);         // writes h
    if (t + 1 < OBS_LEN) STAGE_OBS(t + 1, posL[(t + 1) & 1]);
    __syncthreads();                 // h + staged pos visible
  }

  // ---- enc -> dec transition ----
  LOADW(wt_dec, aux_dec);
#pragma unroll
  for (int m = 0; m < 4; ++m) {
#pragma unroll
    for (int r = 0; r < 4; ++r) cr[m][r] = 0.f;
  }
  POS_PHASE(0);                      // pos0 from h_enc; writes posL[0]

  // ---- decoder ----
  for (int s = 1; s < PRED_LEN; ++s) {
    __syncthreads();                 // posL[0] visible
    STEP_MM();
    __syncthreads();                 // all waves done reading Als
    GATE_PHASE(posL[0]);
    __syncthreads();                 // h visible
    POS_PHASE(s);
  }
}

extern "C" void kernel_launch(void* const* d_in, const int* in_sizes, int n_in,
                              void* d_out, int out_size, void* d_ws, size_t ws_size,
                              hipStream_t stream) {
  const float* obs   = (const float*)d_in[0];
  const float* We    = (const float*)d_in[1];
  const float* be    = (const float*)d_in[2];
  const float* Wih_e = (const float*)d_in[3];
  const float* Whh_e = (const float*)d_in[4];
  const float* b_e   = (const float*)d_in[5];
  const float* Wd    = (const float*)d_in[6];
  const float* bd    = (const float*)d_in[7];
  const float* Wih_d = (const float*)d_in[8];
  const float* Whh_d = (const float*)d_in[9];
  const float* b_d   = (const float*)d_in[10];
  const float* Wo    = (const float*)d_in[11];
  const float* bo    = (const float*)d_in[12];
  float* out = (float*)d_out;

  unsigned short* wt_enc = (unsigned short*)d_ws;                 // 512*128*2 = 128 KB
  unsigned short* wt_dec = wt_enc + NZ * KWT;                     // +128 KB
  float* aux_enc = (float*)(wt_dec + NZ * KWT);                   // 3*512*4 = 6 KB
  float* aux_dec = aux_enc + 3 * NZ;

  hipLaunchKernelGGL(prep_weights, dim3(2 * NZ), dim3(64), 0, stream,
                     We, be, Wih_e, Whh_e, b_e, Wd, bd, Wih_d, Whh_d, b_d,
                     wt_enc, wt_dec, aux_enc, aux_dec);
  hipLaunchKernelGGL(lstm_fused, dim3(BATCH / ROWS), dim3(512), 0, stream,
                     obs, wt_enc, wt_dec, aux_enc, aux_dec, Wo, bo, out);
}